// Round 4
// baseline (18016.631 us; speedup 1.0000x reference)
//
#include <hip/hip_runtime.h>
#include <hip/hip_bf16.h>

#define TSTEPS 2048
#define HD     1024
#define BATCH  8
#define NCLS   64
#define NBLK   32          // persistent blocks, 1024 threads each
#define UPR    32          // units per block (16 waves x 2)

// workspace byte offsets
#define OFF_WC    0              // u32 [NBLK][16][8][512] = 8 MiB packed bf16x2
#define OFF_BIAS  8388608        // f32 [4096]
#define OFF_HS2   8404992        // u32 [TSTEPS+1][HD] (bf16 val<<16 | step tag)

__device__ __forceinline__ float blo(unsigned u) { return __uint_as_float(u << 16); }
__device__ __forceinline__ float bhi(unsigned u) { return __uint_as_float(u & 0xffff0000u); }
__device__ __forceinline__ float sigf(float x) { return 1.f / (1.f + __expf(-x)); }
__device__ __forceinline__ float tanhfast(float x) {
    float e = __expf(2.f * x);
    return 1.f - 2.f / (e + 1.f);
}
__device__ __forceinline__ unsigned f32_to_bf16_rne(float f) {
    unsigned u = __float_as_uint(f);
    return (u + 0x7fffu + ((u >> 16) & 1u)) >> 16;
}
__device__ __forceinline__ void st_rlx_u64(unsigned long long* p, unsigned long long v) {
    __hip_atomic_store(p, v, __ATOMIC_RELAXED, __HIP_MEMORY_SCOPE_AGENT);
}
__device__ __forceinline__ unsigned ld_rlx_u32(const unsigned* p) {
    return __hip_atomic_load((unsigned*)p, __ATOMIC_RELAXED, __HIP_MEMORY_SCOPE_AGENT);
}

// ---- prep 1: bias sum, init hs2 row 0 (val=0, tag=0) ----
__global__ void prep_misc(const float* __restrict__ bih, const float* __restrict__ bhh,
                          float* __restrict__ bias, unsigned* hs2) {
    int idx = blockIdx.x * 256 + threadIdx.x;
    if (idx < 4096) bias[idx] = bih[idx] + bhh[idx];
    if (idx < HD)   hs2[idx] = 0u;
}

// ---- prep 2: pack bf16x2 weights per-(blk,wave,row,lane) ----
// word addr = ((blk*16 + wv)*8 + rr)*512 + m*64 + l
// lane l of wave wv holds row elems k = j*64 + l (j=0..15); word m packs j=2m (lo), j=2m+1 (hi)
__global__ void prep_wc(const float* __restrict__ wih, const float* __restrict__ whh,
                        unsigned* __restrict__ wc) {
    int idx = blockIdx.x * 256 + threadIdx.x;      // 0 .. 2^21
    int l   = idx & 63;
    int m   = (idx >> 6) & 7;
    int rr  = (idx >> 9) & 7;
    int wv  = (idx >> 12) & 15;
    int blk = idx >> 16;
    int gate = rr & 3;
    int unit = blk * UPR + wv * 2 + (rr >> 2);
    int grow = gate * 1024 + unit;
    int k0 = 128 * m + l;
    int k1 = 128 * m + 64 + l;
    unsigned lo = f32_to_bf16_rne(wih[(size_t)grow * 1024 + k0] + whh[(size_t)grow * 1024 + k0]);
    unsigned hi = f32_to_bf16_rne(wih[(size_t)grow * 1024 + k1] + whh[(size_t)grow * 1024 + k1]);
    wc[idx] = lo | (hi << 16);
}

// ---- persistent LSTM: 32 blocks x 1024 threads, weights in VGPRs ----
__global__ __launch_bounds__(1024) void lstm_kernel(const unsigned* __restrict__ wc,
                                                    const float* __restrict__ bias,
                                                    unsigned* hs2) {
    __shared__ unsigned hbuf[HD];     // packed (bf16|tag) row t

    const int tid = threadIdx.x;
    const int w   = tid >> 6;         // wave 0..15
    const int l   = tid & 63;
    const int blk = blockIdx.x;

    // weights into registers: 8 rows x 8 packed bf16x2 words per lane (64 VGPR)
    unsigned wreg[8][8];
    {
        const unsigned* wbase = wc + ((size_t)(blk * 16 + w) * 8) * 512;
        #pragma unroll
        for (int rr = 0; rr < 8; ++rr)
            #pragma unroll
            for (int m = 0; m < 8; ++m)
                wreg[rr][m] = wbase[rr * 512 + m * 64 + l];
    }
    float brow[8];
    #pragma unroll
    for (int rr = 0; rr < 8; ++rr)
        brow[rr] = bias[(rr & 3) * 1024 + blk * UPR + 2 * w + (rr >> 2)];

    const int ubase = blk * UPR + 2 * w;
    float c0 = 0.f, c1 = 0.f;

    for (int t = 0; t < TSTEPS; ++t) {
        // each thread polls exactly ONE word of row t; lanes that got their
        // word drop out of the loop (exec-masked), so re-reads touch only
        // laggard words. s_sleep(1)=64cy backoff decongests the MALL.
        {
            const unsigned tt = (unsigned)t;
            const unsigned* p = hs2 + (size_t)t * HD + tid;
            unsigned q = ld_rlx_u32(p);
            while ((q & 0xffffu) != tt) {
                __builtin_amdgcn_s_sleep(1);
                q = ld_rlx_u32(p);
            }
            hbuf[tid] = q;
        }
        __syncthreads();

        // h elems k = j*64 + l : stride-64 word reads, conflict-free
        float hf[16];
        #pragma unroll
        for (int j = 0; j < 16; ++j) hf[j] = bhi(hbuf[j * 64 + l]);

        // 8 gate-row partial dots from register-held weights
        float accs[8];
        #pragma unroll
        for (int rr = 0; rr < 8; ++rr) {
            float a = 0.f;
            #pragma unroll
            for (int m = 0; m < 8; ++m) {
                unsigned wv = wreg[rr][m];
                a = fmaf(blo(wv), hf[2 * m], a);
                a = fmaf(bhi(wv), hf[2 * m + 1], a);
            }
            accs[rr] = a;
        }
        #pragma unroll
        for (int rr = 0; rr < 8; ++rr) {
            float a = accs[rr];
            a += __shfl_xor(a, 32); a += __shfl_xor(a, 16); a += __shfl_xor(a, 8);
            a += __shfl_xor(a, 4);  a += __shfl_xor(a, 2);  a += __shfl_xor(a, 1);
            accs[rr] = a + brow[rr];
        }
        // gate order i,f,g,o ; two units per wave
        float ii0 = sigf(accs[0]), ff0 = sigf(accs[1]), gg0 = tanhfast(accs[2]), oo0 = sigf(accs[3]);
        c0 = ff0 * c0 + ii0 * gg0;
        float h0 = oo0 * tanhfast(c0);
        float ii1 = sigf(accs[4]), ff1 = sigf(accs[5]), gg1 = tanhfast(accs[6]), oo1 = sigf(accs[7]);
        c1 = ff1 * c1 + ii1 * gg1;
        float h1 = oo1 * tanhfast(c1);

        // publish both units as one u64 (data-carried tag: no fence needed)
        if (l == 0) {
            unsigned tag = (unsigned)(t + 1);
            unsigned p0 = (f32_to_bf16_rne(h0) << 16) | tag;
            unsigned p1 = (f32_to_bf16_rne(h1) << 16) | tag;
            st_rlx_u64((unsigned long long*)(hs2 + (size_t)(t + 1) * HD + ubase),
                       ((unsigned long long)p1 << 32) | p0);
        }
        // no second barrier needed: successful poll of row t+1 implies every
        // in-block wave already stored (hence finished reading hbuf for) row t.
    }
}

// ---- epilogue: neck[b][c][t] = (x[b][c][t] + h[t][c]) * mask[b][t] ----
__global__ void neck_kernel(const float* __restrict__ x, const float* __restrict__ masks,
                            const unsigned* __restrict__ hs2, float* __restrict__ out) {
    int t0 = blockIdx.x * 64, c0 = blockIdx.y * 32;
    __shared__ float tile[32][65];
    int tid = threadIdx.x;
    for (int i = tid; i < 64 * 32; i += 256) {
        int tl = i >> 5, cl = i & 31;
        tile[cl][tl] = bhi(hs2[(size_t)(t0 + tl + 1) * HD + c0 + cl]);
    }
    __syncthreads();
    int tl = tid & 63, cb = tid >> 6;
    for (int b = 0; b < BATCH; ++b) {
        float m = masks[b * TSTEPS + t0 + tl];
        #pragma unroll
        for (int cc = cb; cc < 32; cc += 4) {
            size_t idx = ((size_t)b * 1024 + (c0 + cc)) * TSTEPS + t0 + tl;
            out[idx] = (x[idx] + tile[cc][tl]) * m;
        }
    }
}

// ---- epilogue: frames[b][t][n] = (h[t] . W_fc[n] + b_fc[n]) * mask[b][t] ----
__global__ void frames_kernel(const unsigned* __restrict__ hs2, const float* __restrict__ wfc,
                              const float* __restrict__ bfc, const float* __restrict__ masks,
                              float* __restrict__ out2) {
    int t = blockIdx.x;
    __shared__ float hrow[HD];
    int tid = threadIdx.x;
    for (int i = tid; i < HD; i += 256) hrow[i] = bhi(hs2[(size_t)(t + 1) * HD + i]);
    __syncthreads();
    int n = tid >> 2, p = tid & 3;
    const float* wr = wfc + n * HD + p * 256;
    const float* hr = hrow + p * 256;
    float acc = 0.f;
    #pragma unroll 8
    for (int j = 0; j < 256; ++j) acc = fmaf(wr[j], hr[j], acc);
    acc += __shfl_xor(acc, 1);
    acc += __shfl_xor(acc, 2);
    float v = acc + bfc[n];
    if (p == 0) {
        for (int b = 0; b < BATCH; ++b) {
            float m = masks[b * TSTEPS + t];
            out2[((size_t)b * TSTEPS + t) * NCLS + n] = v * m;
        }
    }
}

extern "C" void kernel_launch(void* const* d_in, const int* in_sizes, int n_in,
                              void* d_out, int out_size, void* d_ws, size_t ws_size,
                              hipStream_t stream) {
    const float* x     = (const float*)d_in[0];
    const float* masks = (const float*)d_in[1];
    const float* wih   = (const float*)d_in[2];
    const float* whh   = (const float*)d_in[3];
    const float* bih   = (const float*)d_in[4];
    const float* bhh   = (const float*)d_in[5];
    const float* wfc   = (const float*)d_in[6];
    const float* bfc   = (const float*)d_in[7];
    float* out = (float*)d_out;

    char* ws = (char*)d_ws;
    unsigned* wc  = (unsigned*)(ws + OFF_WC);
    float* bias   = (float*)(ws + OFF_BIAS);
    unsigned* hs2 = (unsigned*)(ws + OFF_HS2);

    hipLaunchKernelGGL(prep_misc, dim3(16), dim3(256), 0, stream, bih, bhh, bias, hs2);
    hipLaunchKernelGGL(prep_wc, dim3(8192), dim3(256), 0, stream, wih, whh, wc);
    hipLaunchKernelGGL(lstm_kernel, dim3(NBLK), dim3(1024), 0, stream, wc, bias, hs2);
    hipLaunchKernelGGL(neck_kernel, dim3(32, 32), dim3(256), 0, stream, x, masks, hs2, out);
    hipLaunchKernelGGL(frames_kernel, dim3(2048), dim3(256), 0, stream, hs2, wfc, bfc, masks,
                       out + (size_t)BATCH * 1024 * TSTEPS);
}

// Round 5
// 15710.635 us; speedup vs baseline: 1.1468x; 1.1468x over previous
//
#include <hip/hip_runtime.h>
#include <hip/hip_bf16.h>

#define TSTEPS 2048
#define HD     1024
#define BATCH  8
#define NCLS   64
#define NBLK   32          // persistent blocks, 1024 threads each
#define UPR    32          // units per block (16 waves x 2)

// workspace byte offsets
#define OFF_WC    0              // u32 [NBLK][16][8][512] = 8 MiB packed bf16x2
#define OFF_BIAS  8388608        // f32 [4096]
#define OFF_HS2   8404992        // u32 [TSTEPS+1][HD] (bf16 val<<16 | step tag)

__device__ __forceinline__ float blo(unsigned u) { return __uint_as_float(u << 16); }
__device__ __forceinline__ float bhi(unsigned u) { return __uint_as_float(u & 0xffff0000u); }
__device__ __forceinline__ float sigf(float x) { return 1.f / (1.f + __expf(-x)); }
__device__ __forceinline__ float tanhfast(float x) {
    float e = __expf(2.f * x);
    return 1.f - 2.f / (e + 1.f);
}
__device__ __forceinline__ unsigned f32_to_bf16_rne(float f) {
    unsigned u = __float_as_uint(f);
    return (u + 0x7fffu + ((u >> 16) & 1u)) >> 16;
}
__device__ __forceinline__ void st_rlx_u64(unsigned long long* p, unsigned long long v) {
    __hip_atomic_store(p, v, __ATOMIC_RELAXED, __HIP_MEMORY_SCOPE_AGENT);
}
__device__ __forceinline__ unsigned ld_rlx_u32(const unsigned* p) {
    return __hip_atomic_load((unsigned*)p, __ATOMIC_RELAXED, __HIP_MEMORY_SCOPE_AGENT);
}

// ---- prep 1: bias sum, init hs2 row 0 (val=0, tag=0) ----
__global__ void prep_misc(const float* __restrict__ bih, const float* __restrict__ bhh,
                          float* __restrict__ bias, unsigned* hs2) {
    int idx = blockIdx.x * 256 + threadIdx.x;
    if (idx < 4096) bias[idx] = bih[idx] + bhh[idx];
    if (idx < HD)   hs2[idx] = 0u;
}

// ---- prep 2: pack bf16x2 weights per-(blk,wave,row,lane) ----
// word addr = ((blk*16 + wv)*8 + rr)*512 + m*64 + l
// lane l of wave wv holds row elems k = j*64 + l (j=0..15); word m packs j=2m (lo), j=2m+1 (hi)
__global__ void prep_wc(const float* __restrict__ wih, const float* __restrict__ whh,
                        unsigned* __restrict__ wc) {
    int idx = blockIdx.x * 256 + threadIdx.x;      // 0 .. 2^21
    int l   = idx & 63;
    int m   = (idx >> 6) & 7;
    int rr  = (idx >> 9) & 7;
    int wv  = (idx >> 12) & 15;
    int blk = idx >> 16;
    int gate = rr & 3;
    int unit = blk * UPR + wv * 2 + (rr >> 2);
    int grow = gate * 1024 + unit;
    int k0 = 128 * m + l;
    int k1 = 128 * m + 64 + l;
    unsigned lo = f32_to_bf16_rne(wih[(size_t)grow * 1024 + k0] + whh[(size_t)grow * 1024 + k0]);
    unsigned hi = f32_to_bf16_rne(wih[(size_t)grow * 1024 + k1] + whh[(size_t)grow * 1024 + k1]);
    wc[idx] = lo | (hi << 16);
}

// ---- persistent LSTM: 32 blocks x 1024 threads, weights in VGPRs ----
// __launch_bounds__(1024, 4): 4 waves/EU min -> VGPR cap 128 (NOT 64) -> no weight spill
__global__ __launch_bounds__(1024, 4) void lstm_kernel(const unsigned* __restrict__ wc,
                                                       const float* __restrict__ bias,
                                                       unsigned* hs2) {
    __shared__ unsigned hbuf[HD];     // packed (bf16|tag) row t
    __shared__ unsigned stage[UPR];   // block's 32 outgoing packed words

    const int tid = threadIdx.x;
    const int w   = tid >> 6;         // wave 0..15
    const int l   = tid & 63;
    const int blk = blockIdx.x;

    // weights into registers: 8 rows x 8 packed bf16x2 words per lane (64 VGPR)
    unsigned wreg[8][8];
    {
        const unsigned* wbase = wc + ((size_t)(blk * 16 + w) * 8) * 512;
        #pragma unroll
        for (int rr = 0; rr < 8; ++rr)
            #pragma unroll
            for (int m = 0; m < 8; ++m)
                wreg[rr][m] = wbase[rr * 512 + m * 64 + l];
    }
    float brow[8];
    #pragma unroll
    for (int rr = 0; rr < 8; ++rr)
        brow[rr] = bias[(rr & 3) * 1024 + blk * UPR + 2 * w + (rr >> 2)];

    float c0 = 0.f, c1 = 0.f;

    for (int t = 0; t < TSTEPS; ++t) {
        // each thread polls exactly ONE word of row t; satisfied lanes drop out
        {
            const unsigned tt = (unsigned)t;
            const unsigned* p = hs2 + (size_t)t * HD + tid;
            unsigned q = ld_rlx_u32(p);
            while ((q & 0xffffu) != tt) {
                __builtin_amdgcn_s_sleep(1);
                q = ld_rlx_u32(p);
            }
            hbuf[tid] = q;
        }
        __syncthreads();

        // h elems k = j*64 + l : stride-64 word reads, conflict-free
        float hf[16];
        #pragma unroll
        for (int j = 0; j < 16; ++j) hf[j] = bhi(hbuf[j * 64 + l]);

        // 8 gate-row partial dots from register-held weights
        float accs[8];
        #pragma unroll
        for (int rr = 0; rr < 8; ++rr) {
            float a = 0.f;
            #pragma unroll
            for (int m = 0; m < 8; ++m) {
                unsigned wv = wreg[rr][m];
                a = fmaf(blo(wv), hf[2 * m], a);
                a = fmaf(bhi(wv), hf[2 * m + 1], a);
            }
            accs[rr] = a;
        }
        #pragma unroll
        for (int rr = 0; rr < 8; ++rr) {
            float a = accs[rr];
            a += __shfl_xor(a, 32); a += __shfl_xor(a, 16); a += __shfl_xor(a, 8);
            a += __shfl_xor(a, 4);  a += __shfl_xor(a, 2);  a += __shfl_xor(a, 1);
            accs[rr] = a + brow[rr];
        }
        // gate order i,f,g,o ; two units per wave
        float ii0 = sigf(accs[0]), ff0 = sigf(accs[1]), gg0 = tanhfast(accs[2]), oo0 = sigf(accs[3]);
        c0 = ff0 * c0 + ii0 * gg0;
        float h0 = oo0 * tanhfast(c0);
        float ii1 = sigf(accs[4]), ff1 = sigf(accs[5]), gg1 = tanhfast(accs[6]), oo1 = sigf(accs[7]);
        c1 = ff1 * c1 + ii1 * gg1;
        float h1 = oo1 * tanhfast(c1);

        // stage the block's 32 packed words in LDS, then ONE wave ships all 128B:
        // writers per step drop 512 -> 32; each MALL line has a single writer wave.
        {
            unsigned tag = (unsigned)(t + 1);
            if (l == 0) {
                stage[2 * w]     = (f32_to_bf16_rne(h0) << 16) | tag;
                stage[2 * w + 1] = (f32_to_bf16_rne(h1) << 16) | tag;
            }
        }
        __syncthreads();   // also protects hbuf reuse at t+1
        if (tid < 16) {
            unsigned long long v = ((const unsigned long long*)stage)[tid];
            st_rlx_u64((unsigned long long*)(hs2 + (size_t)(t + 1) * HD + blk * UPR) + tid, v);
        }
    }
}

// ---- epilogue: neck[b][c][t] = (x[b][c][t] + h[t][c]) * mask[b][t] ----
__global__ void neck_kernel(const float* __restrict__ x, const float* __restrict__ masks,
                            const unsigned* __restrict__ hs2, float* __restrict__ out) {
    int t0 = blockIdx.x * 64, c0 = blockIdx.y * 32;
    __shared__ float tile[32][65];
    int tid = threadIdx.x;
    for (int i = tid; i < 64 * 32; i += 256) {
        int tl = i >> 5, cl = i & 31;
        tile[cl][tl] = bhi(hs2[(size_t)(t0 + tl + 1) * HD + c0 + cl]);
    }
    __syncthreads();
    int tl = tid & 63, cb = tid >> 6;
    for (int b = 0; b < BATCH; ++b) {
        float m = masks[b * TSTEPS + t0 + tl];
        #pragma unroll
        for (int cc = cb; cc < 32; cc += 4) {
            size_t idx = ((size_t)b * 1024 + (c0 + cc)) * TSTEPS + t0 + tl;
            out[idx] = (x[idx] + tile[cc][tl]) * m;
        }
    }
}

// ---- epilogue: frames[b][t][n] = (h[t] . W_fc[n] + b_fc[n]) * mask[b][t] ----
__global__ void frames_kernel(const unsigned* __restrict__ hs2, const float* __restrict__ wfc,
                              const float* __restrict__ bfc, const float* __restrict__ masks,
                              float* __restrict__ out2) {
    int t = blockIdx.x;
    __shared__ float hrow[HD];
    int tid = threadIdx.x;
    for (int i = tid; i < HD; i += 256) hrow[i] = bhi(hs2[(size_t)(t + 1) * HD + i]);
    __syncthreads();
    int n = tid >> 2, p = tid & 3;
    const float* wr = wfc + n * HD + p * 256;
    const float* hr = hrow + p * 256;
    float acc = 0.f;
    #pragma unroll 8
    for (int j = 0; j < 256; ++j) acc = fmaf(wr[j], hr[j], acc);
    acc += __shfl_xor(acc, 1);
    acc += __shfl_xor(acc, 2);
    float v = acc + bfc[n];
    if (p == 0) {
        for (int b = 0; b < BATCH; ++b) {
            float m = masks[b * TSTEPS + t];
            out2[((size_t)b * TSTEPS + t) * NCLS + n] = v * m;
        }
    }
}

extern "C" void kernel_launch(void* const* d_in, const int* in_sizes, int n_in,
                              void* d_out, int out_size, void* d_ws, size_t ws_size,
                              hipStream_t stream) {
    const float* x     = (const float*)d_in[0];
    const float* masks = (const float*)d_in[1];
    const float* wih   = (const float*)d_in[2];
    const float* whh   = (const float*)d_in[3];
    const float* bih   = (const float*)d_in[4];
    const float* bhh   = (const float*)d_in[5];
    const float* wfc   = (const float*)d_in[6];
    const float* bfc   = (const float*)d_in[7];
    float* out = (float*)d_out;

    char* ws = (char*)d_ws;
    unsigned* wc  = (unsigned*)(ws + OFF_WC);
    float* bias   = (float*)(ws + OFF_BIAS);
    unsigned* hs2 = (unsigned*)(ws + OFF_HS2);

    hipLaunchKernelGGL(prep_misc, dim3(16), dim3(256), 0, stream, bih, bhh, bias, hs2);
    hipLaunchKernelGGL(prep_wc, dim3(8192), dim3(256), 0, stream, wih, whh, wc);
    hipLaunchKernelGGL(lstm_kernel, dim3(NBLK), dim3(1024), 0, stream, wc, bias, hs2);
    hipLaunchKernelGGL(neck_kernel, dim3(32, 32), dim3(256), 0, stream, x, masks, hs2, out);
    hipLaunchKernelGGL(frames_kernel, dim3(2048), dim3(256), 0, stream, hs2, wfc, bfc, masks,
                       out + (size_t)BATCH * 1024 * TSTEPS);
}

// Round 6
// 15669.740 us; speedup vs baseline: 1.1498x; 1.0026x over previous
//
#include <hip/hip_runtime.h>
#include <hip/hip_bf16.h>

#define TSTEPS 2048
#define HD     1024
#define BATCH  8
#define NCLS   64
#define NBLK   32          // persistent blocks, 1024 threads each
#define UPR    32          // units per block (16 waves x 2)

// workspace byte offsets
#define OFF_WC    0              // u32 [NBLK][16][8][512] = 8 MiB packed bf16x2
#define OFF_BIAS  8388608        // f32 [4096]
#define OFF_HS2   8404992        // u32 [TSTEPS+1][HD] (bf16 val<<16 | step tag)

__device__ __forceinline__ float blo(unsigned u) { return __uint_as_float(u << 16); }
__device__ __forceinline__ float bhi(unsigned u) { return __uint_as_float(u & 0xffff0000u); }
__device__ __forceinline__ float sigf(float x) { return 1.f / (1.f + __expf(-x)); }
__device__ __forceinline__ float tanhfast(float x) {
    float e = __expf(2.f * x);
    return 1.f - 2.f / (e + 1.f);
}
__device__ __forceinline__ unsigned f32_to_bf16_rne(float f) {
    unsigned u = __float_as_uint(f);
    return (u + 0x7fffu + ((u >> 16) & 1u)) >> 16;
}
__device__ __forceinline__ void st_rlx_u64(unsigned long long* p, unsigned long long v) {
    __hip_atomic_store(p, v, __ATOMIC_RELAXED, __HIP_MEMORY_SCOPE_AGENT);
}
__device__ __forceinline__ unsigned ld_rlx_u32(const unsigned* p) {
    return __hip_atomic_load((unsigned*)p, __ATOMIC_RELAXED, __HIP_MEMORY_SCOPE_AGENT);
}

// ---- prep 1: bias sum, init hs2 row 0 (val=0, tag=0) ----
__global__ void prep_misc(const float* __restrict__ bih, const float* __restrict__ bhh,
                          float* __restrict__ bias, unsigned* hs2) {
    int idx = blockIdx.x * 256 + threadIdx.x;
    if (idx < 4096) bias[idx] = bih[idx] + bhh[idx];
    if (idx < HD)   hs2[idx] = 0u;
}

// ---- prep 2: pack bf16x2 weights per-(blk,wave,row,lane) ----
// word addr = ((blk*16 + wv)*8 + rr)*512 + m*64 + l
// lane l of wave wv holds row elems k = j*64 + l (j=0..15); word m packs j=2m (lo), j=2m+1 (hi)
__global__ void prep_wc(const float* __restrict__ wih, const float* __restrict__ whh,
                        unsigned* __restrict__ wc) {
    int idx = blockIdx.x * 256 + threadIdx.x;      // 0 .. 2^21
    int l   = idx & 63;
    int m   = (idx >> 6) & 7;
    int rr  = (idx >> 9) & 7;
    int wv  = (idx >> 12) & 15;
    int blk = idx >> 16;
    int gate = rr & 3;
    int unit = blk * UPR + wv * 2 + (rr >> 2);
    int grow = gate * 1024 + unit;
    int k0 = 128 * m + l;
    int k1 = 128 * m + 64 + l;
    unsigned lo = f32_to_bf16_rne(wih[(size_t)grow * 1024 + k0] + whh[(size_t)grow * 1024 + k0]);
    unsigned hi = f32_to_bf16_rne(wih[(size_t)grow * 1024 + k1] + whh[(size_t)grow * 1024 + k1]);
    wc[idx] = lo | (hi << 16);
}

// ---- persistent LSTM: 32 blocks x 1024 threads, weights in VGPRs ----
// __launch_bounds__(1024, 1): CUDA semantics = min 1 BLOCK per CU -> 16 waves/CU
// = 4 waves/EU -> VGPR cap 128. (R4/R5's default/(,4) gave 2 blocks/CU -> cap 64
// -> the 64-word wreg spilled to scratch; VGPR_Count==64 was the tell.)
__global__ __launch_bounds__(1024, 1) void lstm_kernel(const unsigned* __restrict__ wc,
                                                       const float* __restrict__ bias,
                                                       unsigned* hs2) {
    __shared__ unsigned hbuf[HD];     // packed (bf16|tag) row t
    __shared__ unsigned stage[UPR];   // block's 32 outgoing packed words

    const int tid = threadIdx.x;
    const int w   = tid >> 6;         // wave 0..15
    const int l   = tid & 63;
    const int blk = blockIdx.x;

    // weights into registers: 8 rows x 8 packed bf16x2 words per lane (64 VGPR)
    unsigned wreg[8][8];
    {
        const unsigned* wbase = wc + ((size_t)(blk * 16 + w) * 8) * 512;
        #pragma unroll
        for (int rr = 0; rr < 8; ++rr)
            #pragma unroll
            for (int m = 0; m < 8; ++m)
                wreg[rr][m] = wbase[rr * 512 + m * 64 + l];
    }
    float brow[8];
    #pragma unroll
    for (int rr = 0; rr < 8; ++rr)
        brow[rr] = bias[(rr & 3) * 1024 + blk * UPR + 2 * w + (rr >> 2)];

    float c0 = 0.f, c1 = 0.f;

    for (int t = 0; t < TSTEPS; ++t) {
        // each thread polls exactly ONE word of row t; satisfied lanes drop out
        {
            const unsigned tt = (unsigned)t;
            const unsigned* p = hs2 + (size_t)t * HD + tid;
            unsigned q = ld_rlx_u32(p);
            while ((q & 0xffffu) != tt) {
                __builtin_amdgcn_s_sleep(1);
                q = ld_rlx_u32(p);
            }
            hbuf[tid] = q;
        }
        __syncthreads();

        // h elems k = j*64 + l : stride-64 word reads, conflict-free
        float hf[16];
        #pragma unroll
        for (int j = 0; j < 16; ++j) hf[j] = bhi(hbuf[j * 64 + l]);

        // 8 gate-row partial dots from register-held weights
        float accs[8];
        #pragma unroll
        for (int rr = 0; rr < 8; ++rr) {
            float a = 0.f;
            #pragma unroll
            for (int m = 0; m < 8; ++m) {
                unsigned wv = wreg[rr][m];
                a = fmaf(blo(wv), hf[2 * m], a);
                a = fmaf(bhi(wv), hf[2 * m + 1], a);
            }
            accs[rr] = a;
        }
        #pragma unroll
        for (int rr = 0; rr < 8; ++rr) {
            float a = accs[rr];
            a += __shfl_xor(a, 32); a += __shfl_xor(a, 16); a += __shfl_xor(a, 8);
            a += __shfl_xor(a, 4);  a += __shfl_xor(a, 2);  a += __shfl_xor(a, 1);
            accs[rr] = a + brow[rr];
        }
        // gate order i,f,g,o ; two units per wave
        float ii0 = sigf(accs[0]), ff0 = sigf(accs[1]), gg0 = tanhfast(accs[2]), oo0 = sigf(accs[3]);
        c0 = ff0 * c0 + ii0 * gg0;
        float h0 = oo0 * tanhfast(c0);
        float ii1 = sigf(accs[4]), ff1 = sigf(accs[5]), gg1 = tanhfast(accs[6]), oo1 = sigf(accs[7]);
        c1 = ff1 * c1 + ii1 * gg1;
        float h1 = oo1 * tanhfast(c1);

        // stage the block's 32 packed words in LDS, then ONE wave ships all 128B
        {
            unsigned tag = (unsigned)(t + 1);
            if (l == 0) {
                stage[2 * w]     = (f32_to_bf16_rne(h0) << 16) | tag;
                stage[2 * w + 1] = (f32_to_bf16_rne(h1) << 16) | tag;
            }
        }
        __syncthreads();   // also protects hbuf reuse at t+1
        if (tid < 16) {
            unsigned long long v = ((const unsigned long long*)stage)[tid];
            st_rlx_u64((unsigned long long*)(hs2 + (size_t)(t + 1) * HD + blk * UPR) + tid, v);
        }
    }
}

// ---- epilogue: neck[b][c][t] = (x[b][c][t] + h[t][c]) * mask[b][t] ----
__global__ void neck_kernel(const float* __restrict__ x, const float* __restrict__ masks,
                            const unsigned* __restrict__ hs2, float* __restrict__ out) {
    int t0 = blockIdx.x * 64, c0 = blockIdx.y * 32;
    __shared__ float tile[32][65];
    int tid = threadIdx.x;
    for (int i = tid; i < 64 * 32; i += 256) {
        int tl = i >> 5, cl = i & 31;
        tile[cl][tl] = bhi(hs2[(size_t)(t0 + tl + 1) * HD + c0 + cl]);
    }
    __syncthreads();
    int tl = tid & 63, cb = tid >> 6;
    for (int b = 0; b < BATCH; ++b) {
        float m = masks[b * TSTEPS + t0 + tl];
        #pragma unroll
        for (int cc = cb; cc < 32; cc += 4) {
            size_t idx = ((size_t)b * 1024 + (c0 + cc)) * TSTEPS + t0 + tl;
            out[idx] = (x[idx] + tile[cc][tl]) * m;
        }
    }
}

// ---- epilogue: frames[b][t][n] = (h[t] . W_fc[n] + b_fc[n]) * mask[b][t] ----
__global__ void frames_kernel(const unsigned* __restrict__ hs2, const float* __restrict__ wfc,
                              const float* __restrict__ bfc, const float* __restrict__ masks,
                              float* __restrict__ out2) {
    int t = blockIdx.x;
    __shared__ float hrow[HD];
    int tid = threadIdx.x;
    for (int i = tid; i < HD; i += 256) hrow[i] = bhi(hs2[(size_t)(t + 1) * HD + i]);
    __syncthreads();
    int n = tid >> 2, p = tid & 3;
    const float* wr = wfc + n * HD + p * 256;
    const float* hr = hrow + p * 256;
    float acc = 0.f;
    #pragma unroll 8
    for (int j = 0; j < 256; ++j) acc = fmaf(wr[j], hr[j], acc);
    acc += __shfl_xor(acc, 1);
    acc += __shfl_xor(acc, 2);
    float v = acc + bfc[n];
    if (p == 0) {
        for (int b = 0; b < BATCH; ++b) {
            float m = masks[b * TSTEPS + t];
            out2[((size_t)b * TSTEPS + t) * NCLS + n] = v * m;
        }
    }
}

extern "C" void kernel_launch(void* const* d_in, const int* in_sizes, int n_in,
                              void* d_out, int out_size, void* d_ws, size_t ws_size,
                              hipStream_t stream) {
    const float* x     = (const float*)d_in[0];
    const float* masks = (const float*)d_in[1];
    const float* wih   = (const float*)d_in[2];
    const float* whh   = (const float*)d_in[3];
    const float* bih   = (const float*)d_in[4];
    const float* bhh   = (const float*)d_in[5];
    const float* wfc   = (const float*)d_in[6];
    const float* bfc   = (const float*)d_in[7];
    float* out = (float*)d_out;

    char* ws = (char*)d_ws;
    unsigned* wc  = (unsigned*)(ws + OFF_WC);
    float* bias   = (float*)(ws + OFF_BIAS);
    unsigned* hs2 = (unsigned*)(ws + OFF_HS2);

    hipLaunchKernelGGL(prep_misc, dim3(16), dim3(256), 0, stream, bih, bhh, bias, hs2);
    hipLaunchKernelGGL(prep_wc, dim3(8192), dim3(256), 0, stream, wih, whh, wc);
    hipLaunchKernelGGL(lstm_kernel, dim3(NBLK), dim3(1024), 0, stream, wc, bias, hs2);
    hipLaunchKernelGGL(neck_kernel, dim3(32, 32), dim3(256), 0, stream, x, masks, hs2, out);
    hipLaunchKernelGGL(frames_kernel, dim3(2048), dim3(256), 0, stream, hs2, wfc, bfc, masks,
                       out + (size_t)BATCH * 1024 * TSTEPS);
}

// Round 7
// 7403.132 us; speedup vs baseline: 2.4336x; 2.1166x over previous
//
#include <hip/hip_runtime.h>
#include <hip/hip_bf16.h>

#define TSTEPS 2048
#define HD     1024
#define BATCH  8
#define NCLS   64
#define NBLK   64          // persistent blocks, 512 threads each, 1 per CU (LDS-bound)
#define UPB    16          // units per block (8 waves x 2)
#define RPB    64          // gate rows per block

// workspace byte offsets
#define OFF_WC    0              // u32 [NBLK][8][8][512] = 8 MiB packed bf16x2
#define OFF_BIAS  8388608        // f32 [4096]
#define OFF_HS2   8404992        // u32 [TSTEPS+1][HD] (bf16 val<<16 | step tag)

__device__ __forceinline__ float blo(unsigned u) { return __uint_as_float(u << 16); }
__device__ __forceinline__ float bhi(unsigned u) { return __uint_as_float(u & 0xffff0000u); }
__device__ __forceinline__ float sigf(float x) { return 1.f / (1.f + __expf(-x)); }
__device__ __forceinline__ float tanhfast(float x) {
    float e = __expf(2.f * x);
    return 1.f - 2.f / (e + 1.f);
}
__device__ __forceinline__ unsigned f32_to_bf16_rne(float f) {
    unsigned u = __float_as_uint(f);
    return (u + 0x7fffu + ((u >> 16) & 1u)) >> 16;
}
__device__ __forceinline__ void st_rlx_u64(unsigned long long* p, unsigned long long v) {
    __hip_atomic_store(p, v, __ATOMIC_RELAXED, __HIP_MEMORY_SCOPE_AGENT);
}
__device__ __forceinline__ unsigned ld_rlx_u32(const unsigned* p) {
    return __hip_atomic_load((unsigned*)p, __ATOMIC_RELAXED, __HIP_MEMORY_SCOPE_AGENT);
}
__device__ __forceinline__ float dot8(uint4 wv, const float* h) {
    float a = 0.f;
    a = fmaf(blo(wv.x), h[0], a); a = fmaf(bhi(wv.x), h[1], a);
    a = fmaf(blo(wv.y), h[2], a); a = fmaf(bhi(wv.y), h[3], a);
    a = fmaf(blo(wv.z), h[4], a); a = fmaf(bhi(wv.z), h[5], a);
    a = fmaf(blo(wv.w), h[6], a); a = fmaf(bhi(wv.w), h[7], a);
    return a;
}

// ---- prep 1: bias sum, init hs2 row 0 (val=0, tag=0) ----
__global__ void prep_misc(const float* __restrict__ bih, const float* __restrict__ bhh,
                          float* __restrict__ bias, unsigned* hs2) {
    int idx = blockIdx.x * 256 + threadIdx.x;
    if (idx < 4096) bias[idx] = bih[idx] + bhh[idx];
    if (idx < HD)   hs2[idx] = 0u;
}

// ---- prep 2: pack bf16x2 weights, row-linear per (blk, wave, local-row) ----
// word addr = ((blk*8 + wv)*8 + rr)*512 + k ; word k packs row elems (2k, 2k+1)
// row = gate*1024 + unit ; gate = rr&3 ; unit = blk*16 + wv*2 + (rr>>2)
__global__ void prep_wc(const float* __restrict__ wih, const float* __restrict__ whh,
                        unsigned* __restrict__ wc) {
    int idx = blockIdx.x * 256 + threadIdx.x;      // 0 .. 2^21
    int k   = idx & 511;
    int rr  = (idx >> 9) & 7;
    int wv  = (idx >> 12) & 7;
    int blk = idx >> 15;
    int gate = rr & 3;
    int unit = blk * UPB + wv * 2 + (rr >> 2);
    size_t grow = (size_t)(gate * 1024 + unit) * 1024;
    unsigned lo = f32_to_bf16_rne(wih[grow + 2 * k]     + whh[grow + 2 * k]);
    unsigned hi = f32_to_bf16_rne(wih[grow + 2 * k + 1] + whh[grow + 2 * k + 1]);
    wc[idx] = lo | (hi << 16);
}

// ---- persistent LSTM: 64 blocks x 512 threads, weights in 128KB LDS ----
__global__ __launch_bounds__(512) void lstm_kernel(const unsigned* __restrict__ wc,
                                                   const float* __restrict__ bias,
                                                   unsigned* hs2) {
    __shared__ unsigned wlds[RPB * 512];   // 128 KiB: [wv*8+rr][512 words]
    __shared__ unsigned hbuf[HD];          // packed (bf16|tag) row t
    __shared__ unsigned stage[UPB];        // block's 16 outgoing packed words

    const int tid = threadIdx.x;
    const int w   = tid >> 6;              // wave 0..7
    const int l   = tid & 63;
    const int blk = blockIdx.x;

    // stage W slice (contiguous 128 KiB) into LDS: 512 thr x 16B x 16 iters
    {
        const uint4* src = (const uint4*)(wc + (size_t)blk * RPB * 512);
        uint4* dst = (uint4*)wlds;
        #pragma unroll
        for (int i = 0; i < 16; ++i) dst[tid + i * 512] = src[tid + i * 512];
    }
    float brow[8];
    #pragma unroll
    for (int rr = 0; rr < 8; ++rr)
        brow[rr] = bias[(rr & 3) * 1024 + blk * UPB + 2 * w + (rr >> 2)];
    __syncthreads();

    float c0 = 0.f, c1 = 0.f;

    for (int t = 0; t < TSTEPS; ++t) {
        // each thread polls TWO words of row t (tid, tid+512); satisfied lanes drop out
        {
            const unsigned tt = (unsigned)t;
            const unsigned* p0 = hs2 + (size_t)t * HD + tid;
            unsigned q = ld_rlx_u32(p0);
            while ((q & 0xffffu) != tt) { __builtin_amdgcn_s_sleep(1); q = ld_rlx_u32(p0); }
            hbuf[tid] = q;
            const unsigned* p1 = p0 + 512;
            q = ld_rlx_u32(p1);
            while ((q & 0xffffu) != tt) { __builtin_amdgcn_s_sleep(1); q = ld_rlx_u32(p1); }
            hbuf[tid + 512] = q;
        }
        __syncthreads();

        // h elems [8l,8l+8) and [512+8l,512+8l+8) from LDS (16B/lane reads)
        float hA[8], hB[8];
        {
            const uint4* hb = (const uint4*)hbuf;
            uint4 a0 = hb[2 * l], a1 = hb[2 * l + 1];
            uint4 b0 = hb[128 + 2 * l], b1 = hb[128 + 2 * l + 1];
            hA[0] = bhi(a0.x); hA[1] = bhi(a0.y); hA[2] = bhi(a0.z); hA[3] = bhi(a0.w);
            hA[4] = bhi(a1.x); hA[5] = bhi(a1.y); hA[6] = bhi(a1.z); hA[7] = bhi(a1.w);
            hB[0] = bhi(b0.x); hB[1] = bhi(b0.y); hB[2] = bhi(b0.z); hB[3] = bhi(b0.w);
            hB[4] = bhi(b1.x); hB[5] = bhi(b1.y); hB[6] = bhi(b1.z); hB[7] = bhi(b1.w);
        }
        // 8 gate-row dot products from LDS-held weights (rows wv*8+rr)
        float accs[8];
        #pragma unroll
        for (int rr = 0; rr < 8; ++rr) {
            const uint4* wrow = (const uint4*)(wlds + (w * 8 + rr) * 512);
            uint4 wa = wrow[l];
            uint4 wb = wrow[64 + l];
            accs[rr] = dot8(wa, hA) + dot8(wb, hB);
        }
        #pragma unroll
        for (int rr = 0; rr < 8; ++rr) {
            float a = accs[rr];
            a += __shfl_xor(a, 32); a += __shfl_xor(a, 16); a += __shfl_xor(a, 8);
            a += __shfl_xor(a, 4);  a += __shfl_xor(a, 2);  a += __shfl_xor(a, 1);
            accs[rr] = a + brow[rr];
        }
        // gate order i,f,g,o ; two units per wave
        float ii0 = sigf(accs[0]), ff0 = sigf(accs[1]), gg0 = tanhfast(accs[2]), oo0 = sigf(accs[3]);
        c0 = ff0 * c0 + ii0 * gg0;
        float h0 = oo0 * tanhfast(c0);
        float ii1 = sigf(accs[4]), ff1 = sigf(accs[5]), gg1 = tanhfast(accs[6]), oo1 = sigf(accs[7]);
        c1 = ff1 * c1 + ii1 * gg1;
        float h1 = oo1 * tanhfast(c1);

        // stage block's 16 packed words, then ONE wave ships 64B as 8 u64 stores
        {
            unsigned tag = (unsigned)(t + 1);
            if (l == 0) {
                stage[2 * w]     = (f32_to_bf16_rne(h0) << 16) | tag;
                stage[2 * w + 1] = (f32_to_bf16_rne(h1) << 16) | tag;
            }
        }
        __syncthreads();   // also protects hbuf reuse at t+1
        if (tid < 8) {
            unsigned long long v = ((const unsigned long long*)stage)[tid];
            st_rlx_u64((unsigned long long*)(hs2 + (size_t)(t + 1) * HD + blk * UPB) + tid, v);
        }
    }
}

// ---- epilogue: neck[b][c][t] = (x[b][c][t] + h[t][c]) * mask[b][t] ----
__global__ void neck_kernel(const float* __restrict__ x, const float* __restrict__ masks,
                            const unsigned* __restrict__ hs2, float* __restrict__ out) {
    int t0 = blockIdx.x * 64, c0 = blockIdx.y * 32;
    __shared__ float tile[32][65];
    int tid = threadIdx.x;
    for (int i = tid; i < 64 * 32; i += 256) {
        int tl = i >> 5, cl = i & 31;
        tile[cl][tl] = bhi(hs2[(size_t)(t0 + tl + 1) * HD + c0 + cl]);
    }
    __syncthreads();
    int tl = tid & 63, cb = tid >> 6;
    for (int b = 0; b < BATCH; ++b) {
        float m = masks[b * TSTEPS + t0 + tl];
        #pragma unroll
        for (int cc = cb; cc < 32; cc += 4) {
            size_t idx = ((size_t)b * 1024 + (c0 + cc)) * TSTEPS + t0 + tl;
            out[idx] = (x[idx] + tile[cc][tl]) * m;
        }
    }
}

// ---- epilogue: frames[b][t][n] = (h[t] . W_fc[n] + b_fc[n]) * mask[b][t] ----
__global__ void frames_kernel(const unsigned* __restrict__ hs2, const float* __restrict__ wfc,
                              const float* __restrict__ bfc, const float* __restrict__ masks,
                              float* __restrict__ out2) {
    int t = blockIdx.x;
    __shared__ float hrow[HD];
    int tid = threadIdx.x;
    for (int i = tid; i < HD; i += 256) hrow[i] = bhi(hs2[(size_t)(t + 1) * HD + i]);
    __syncthreads();
    int n = tid >> 2, p = tid & 3;
    const float* wr = wfc + n * HD + p * 256;
    const float* hr = hrow + p * 256;
    float acc = 0.f;
    #pragma unroll 8
    for (int j = 0; j < 256; ++j) acc = fmaf(wr[j], hr[j], acc);
    acc += __shfl_xor(acc, 1);
    acc += __shfl_xor(acc, 2);
    float v = acc + bfc[n];
    if (p == 0) {
        for (int b = 0; b < BATCH; ++b) {
            float m = masks[b * TSTEPS + t];
            out2[((size_t)b * TSTEPS + t) * NCLS + n] = v * m;
        }
    }
}

extern "C" void kernel_launch(void* const* d_in, const int* in_sizes, int n_in,
                              void* d_out, int out_size, void* d_ws, size_t ws_size,
                              hipStream_t stream) {
    const float* x     = (const float*)d_in[0];
    const float* masks = (const float*)d_in[1];
    const float* wih   = (const float*)d_in[2];
    const float* whh   = (const float*)d_in[3];
    const float* bih   = (const float*)d_in[4];
    const float* bhh   = (const float*)d_in[5];
    const float* wfc   = (const float*)d_in[6];
    const float* bfc   = (const float*)d_in[7];
    float* out = (float*)d_out;

    char* ws = (char*)d_ws;
    unsigned* wc  = (unsigned*)(ws + OFF_WC);
    float* bias   = (float*)(ws + OFF_BIAS);
    unsigned* hs2 = (unsigned*)(ws + OFF_HS2);

    hipLaunchKernelGGL(prep_misc, dim3(16), dim3(256), 0, stream, bih, bhh, bias, hs2);
    hipLaunchKernelGGL(prep_wc, dim3(8192), dim3(256), 0, stream, wih, whh, wc);
    hipLaunchKernelGGL(lstm_kernel, dim3(NBLK), dim3(512), 0, stream, wc, bias, hs2);
    hipLaunchKernelGGL(neck_kernel, dim3(32, 32), dim3(256), 0, stream, x, masks, hs2, out);
    hipLaunchKernelGGL(frames_kernel, dim3(2048), dim3(256), 0, stream, hs2, wfc, bfc, masks,
                       out + (size_t)BATCH * 1024 * TSTEPS);
}